// Round 15
// baseline (159.636 us; speedup 1.0000x reference)
//
#include <hip/hip_runtime.h>

typedef _Float16 f16x4 __attribute__((ext_vector_type(4)));
typedef _Float16 f16x8 __attribute__((ext_vector_type(8)));
typedef __fp16 fp16x2 __attribute__((ext_vector_type(2)));   // cvt_pkrtz return type
typedef float f32x4 __attribute__((ext_vector_type(4)));
typedef float f32x2 __attribute__((ext_vector_type(2)));

#define NBUCKETS 256
#define SSTR 88              // row stride in halves (16B-aligned rows for b128)
#define NROWS 74             // staged rows (64 outputs + 10 halo); rows>=74 only meet zero weights
#define NLD 12               // staging float4 loads per thread (2960/256 = 11.6)

__device__ __forceinline__ f16x4 cvt4(f32x4 a)
{
    union { fp16x2 h2[2]; f16x4 f; } u;
    u.h2[0] = __builtin_amdgcn_cvt_pkrtz(a[0], a[1]);
    u.h2[1] = __builtin_amdgcn_cvt_pkrtz(a[2], a[3]);
    return u.f;
}

// ---- single compute kernel: 64x64 output region per block (2 x 64x32 tiles), 4 waves.
// ONE barrier. H-pass: one mfma_f32_16x16x32_f16 per quantity; D-frag (row=4g+j)
// feeds vertical 16x16x16 B-frags directly in registers (validated R3/R5-R14).
// Quantities: mu1, mu2, A=conv((r+d)^2), B=conv((r-d)^2).
// Weights computed in-block; finalize fused via ordered atomics (NO fences).
__global__ __launch_bounds__(256, 4) void ssim_main(
    const float* __restrict__ raw, const float* __restrict__ dst,
    const float* __restrict__ win, float* __restrict__ buckets,
    float* __restrict__ out, float inv, unsigned nwaves)
{
    __shared__ __align__(16) _Float16 sr[NROWS * SSTR];
    __shared__ __align__(16) _Float16 sd[NROWS * SSTR];
    __shared__ float w1s[11];

    const int tid = threadIdx.x;
    const int wv = tid >> 6;           // wave = 16-wide x-strip
    const int lane = tid & 63;
    const int g = lane >> 4;
    const int ln = lane & 15;
    const int nt = wv;

    const int gx0 = blockIdx.x * 64;
    const int ybase32 = blockIdx.y * 64;        // first input row of the region
    const long ioff = (long)blockIdx.z * (512 * 512);
    const float* rb = raw + ioff;
    const float* db = dst + ioff;

    // 1D gaussian row-sums -> LDS (11 threads; visibility covered by staging barrier)
    if (tid >= 245) {
        int i = tid - 245;             // 0..10
        float s = 0.f;
#pragma unroll
        for (int j = 0; j < 11; ++j) s += win[i * 11 + j];
        w1s[i] = s;
    }

    // ---- staging: 74 rows x {r,d} x 20 float4 chunks = 2960 tasks.
    // Phase 1: issue ALL loads (max MLP); fast path (49/64 blocks) has no clamps.
    // Phase 2: pack f32->f16, write LDS. One barrier total.
    float4 fv[NLD];
    const bool fastpath = (gx0 < 448) && (ybase32 < 448);
    if (fastpath) {
#pragma unroll
        for (int k = 0; k < NLD; ++k) {
            int t = tid + 256 * k;
            if (k < NLD - 1 || t < 2960) {
                int chunk = t % 20;
                int sub = t / 20;          // 0..147
                int row = sub >> 1;        // 0..73
                const float* src = (sub & 1) ? db : rb;
                fv[k] = *reinterpret_cast<const float4*>(
                    src + (long)(ybase32 + row) * 512 + gx0 + 4 * chunk);
            }
        }
    } else {
#pragma unroll
        for (int k = 0; k < NLD; ++k) {
            int t = tid + 256 * k;
            if (k < NLD - 1 || t < 2960) {
                int chunk = t % 20;
                int sub = t / 20;
                int row = sub >> 1;
                int gy = ybase32 + row; if (gy > 511) gy = 511;
                int gxc = gx0 + 4 * chunk; if (gxc > 508) gxc = 508;
                const float* src = (sub & 1) ? db : rb;
                fv[k] = *reinterpret_cast<const float4*>(src + (long)gy * 512 + gxc);
            }
        }
    }
#pragma unroll
    for (int k = 0; k < NLD; ++k) {
        int t = tid + 256 * k;
        if (k < NLD - 1 || t < 2960) {
            int chunk = t % 20;
            int sub = t / 20;
            int row = sub >> 1;
            _Float16* dstp = ((sub & 1) ? sd : sr) + row * SSTR + chunk * 4;
            union { fp16x2 h2[2]; uint2 u; } pk;
            pk.h2[0] = __builtin_amdgcn_cvt_pkrtz(fv[k].x, fv[k].y);
            pk.h2[1] = __builtin_amdgcn_cvt_pkrtz(fv[k].z, fv[k].w);
            *reinterpret_cast<uint2*>(dstp) = pk.u;
        }
    }
    __syncthreads();

    // ---- per-lane weight fragments (banded, translation-invariant; R3/R5+ layout) ----
    f16x4 wf0, wf1;
    f16x8 wh;
    {
        float v[8];
#pragma unroll
        for (int kk = 0; kk < 2; ++kk) {
            int ib = 4 * g + 16 * kk - ln;
#pragma unroll
            for (int j = 0; j < 4; ++j) {
                int idx = ib + j;
                int ci = idx < 0 ? 0 : (idx > 10 ? 10 : idx);
                float t = w1s[ci];
                v[kk * 4 + j] = (idx >= 0 && idx <= 10) ? t : 0.f;
            }
        }
        wf0 = f16x4{(_Float16)v[0], (_Float16)v[1], (_Float16)v[2], (_Float16)v[3]};
        wf1 = f16x4{(_Float16)v[4], (_Float16)v[5], (_Float16)v[6], (_Float16)v[7]};
        float h[8];
#pragma unroll
        for (int j = 0; j < 8; ++j) {
            int idx = 8 * g + j - ln;
            int ci = idx < 0 ? 0 : (idx > 10 ? 10 : idx);
            float t = w1s[ci];
            h[j] = (idx >= 0 && idx <= 10) ? t : 0.f;
        }
        wh = f16x8{(_Float16)h[0], (_Float16)h[1], (_Float16)h[2], (_Float16)h[3],
                   (_Float16)h[4], (_Float16)h[5], (_Float16)h[6], (_Float16)h[7]};
    }

    float lsum = 0.f;
    const int ox = gx0 + 16 * nt + ln;

#pragma unroll
    for (int it = 0; it < 2; ++it) {
        // ---- horizontal conv: ONE 16x16x32 MFMA per quantity per row-tile ----
        f16x4 hf0[4], hf1[4], hf2[4];
#define COMP_H(HF, MT)                                                        \
        {                                                                     \
            f32x4 z = {0, 0, 0, 0};                                           \
            int rrow = ln + 16 * (MT) + 32 * it; if (rrow > 73) rrow = 73;    \
            const f16x8 rA = *(const f16x8*)(sr + rrow * SSTR + 16 * nt + 8 * g); \
            const f16x8 dA = *(const f16x8*)(sd + rrow * SSTR + 16 * nt + 8 * g); \
            f16x8 sA = rA + dA, qA = rA - dA;                                 \
            f16x8 ss = sA * sA, qq = qA * qA;                                 \
            f32x4 a0 = __builtin_amdgcn_mfma_f32_16x16x32_f16(rA, wh, z, 0, 0, 0); \
            f32x4 a1 = __builtin_amdgcn_mfma_f32_16x16x32_f16(dA, wh, z, 0, 0, 0); \
            f32x4 a2 = __builtin_amdgcn_mfma_f32_16x16x32_f16(ss, wh, z, 0, 0, 0); \
            f32x4 a3 = __builtin_amdgcn_mfma_f32_16x16x32_f16(qq, wh, z, 0, 0, 0); \
            HF[0] = cvt4(a0); HF[1] = cvt4(a1); HF[2] = cvt4(a2); HF[3] = cvt4(a3); \
        }
        COMP_H(hf0, 0)
        COMP_H(hf1, 1)
        COMP_H(hf2, 2)
#undef COMP_H

        // ---- vertical conv (2x 16x16x16, register B-frags) + f32x2 epilogue ----
#define COMP_O(HA, HB, MTV)                                                   \
        {                                                                     \
            f32x4 z = {0, 0, 0, 0};                                           \
            f32x4 v0 = __builtin_amdgcn_mfma_f32_16x16x16f16(wf0, HA[0], z, 0, 0, 0); \
            f32x4 v1 = __builtin_amdgcn_mfma_f32_16x16x16f16(wf0, HA[1], z, 0, 0, 0); \
            f32x4 v2 = __builtin_amdgcn_mfma_f32_16x16x16f16(wf0, HA[2], z, 0, 0, 0); \
            f32x4 v3 = __builtin_amdgcn_mfma_f32_16x16x16f16(wf0, HA[3], z, 0, 0, 0); \
            v0 = __builtin_amdgcn_mfma_f32_16x16x16f16(wf1, HB[0], v0, 0, 0, 0); \
            v1 = __builtin_amdgcn_mfma_f32_16x16x16f16(wf1, HB[1], v1, 0, 0, 0); \
            v2 = __builtin_amdgcn_mfma_f32_16x16x16f16(wf1, HB[2], v2, 0, 0, 0); \
            v3 = __builtin_amdgcn_mfma_f32_16x16x16f16(wf1, HB[3], v3, 0, 0, 0); \
            int oy0 = ybase32 + 32 * it + 16 * (MTV) + 4 * g;                 \
            if (ox < 502) {                                                   \
                _Pragma("unroll")                                             \
                for (int p = 0; p < 2; ++p) {                                 \
                    f32x2 m1 = {v0[2*p], v0[2*p+1]};                          \
                    f32x2 m2 = {v1[2*p], v1[2*p+1]};                          \
                    f32x2 A  = {v2[2*p], v2[2*p+1]};                          \
                    f32x2 B  = {v3[2*p], v3[2*p+1]};                          \
                    f32x2 m1s = m1 * m1, m2s = m2 * m2, m12 = m1 * m2;        \
                    f32x2 P = m1s + m2s;                                      \
                    f32x2 num1 = 2.f * m12 + 6.5025f;                         \
                    f32x2 num2 = 0.5f * (A - B) - 2.f * m12 + 58.5225f;       \
                    f32x2 den1 = P + 6.5025f;                                 \
                    f32x2 den2 = 0.5f * (A + B) - P + 58.5225f;               \
                    f32x2 num = num1 * num2, den = den1 * den2;               \
                    if (oy0 + 2*p     < 502) lsum += __fdividef(num[0], den[0]); \
                    if (oy0 + 2*p + 1 < 502) lsum += __fdividef(num[1], den[1]); \
                }                                                             \
            }                                                                 \
        }
        COMP_O(hf0, hf1, 0)
        COMP_O(hf1, hf2, 1)
#undef COMP_O
    }

    // ---- wave reduce -> ordered atomics (NO fences) -> fused finalize ----
#pragma unroll
    for (int off = 32; off; off >>= 1) lsum += __shfl_down(lsum, off);

    unsigned done = 0;
    if (lane == 0) {
        int bucket = ((blockIdx.x + (blockIdx.y << 3) + blockIdx.z * 67) * 4 + wv) & (NBUCKETS - 1);
        float old = atomicAdd(&buckets[bucket], lsum);  // return value forces vmcnt wait
        asm volatile("" : : "v"(old));                  // keep the wait (rule #17)
        done = atomicAdd((unsigned*)(buckets + NBUCKETS), 1u) + 1u;
    }
    done = (unsigned)__shfl((int)done, 0);
    if (done == nwaves) {              // globally-last wave: reduce buckets -> out
        float s = 0.f;
#pragma unroll
        for (int i = 0; i < NBUCKETS / 64; ++i)
            s += atomicAdd(&buckets[lane + 64 * i], 0.f);   // coherent L2 read
#pragma unroll
        for (int off = 32; off; off >>= 1) s += __shfl_down(s, off);
        if (lane == 0) out[0] = s * inv;
    }
}

extern "C" void kernel_launch(void* const* d_in, const int* in_sizes, int n_in,
                              void* d_out, int out_size, void* d_ws, size_t ws_size,
                              hipStream_t stream) {
    const float* raw = (const float*)d_in[0];
    const float* dst = (const float*)d_in[1];
    const float* win = (const float*)d_in[2];
    float* out = (float*)d_out;
    float* ws = (float*)d_ws;

    int nimg = in_sizes[0] / (512 * 512);      // B*C = 48
    float inv = 1.0f / ((float)nimg * 502.f * 502.f);
    unsigned nwaves = 8u * 8u * (unsigned)nimg * 4u;

    // zero buckets + wave counter (in-graph: re-arms every replay)
    hipMemsetAsync(ws, 0, (NBUCKETS + 1) * sizeof(float), stream);
    dim3 grid(8, 8, nimg);
    ssim_main<<<grid, 256, 0, stream>>>(raw, dst, win, ws, out, inv, nwaves);
}

// Round 16
// 58.292 us; speedup vs baseline: 2.7386x; 2.7386x over previous
//
#include <hip/hip_runtime.h>

typedef _Float16 f16x4 __attribute__((ext_vector_type(4)));
typedef _Float16 f16x8 __attribute__((ext_vector_type(8)));
typedef __fp16 fp16x2 __attribute__((ext_vector_type(2)));   // cvt_pkrtz return type
typedef float f32x4 __attribute__((ext_vector_type(4)));
typedef float f32x2 __attribute__((ext_vector_type(2)));

#define SSTR 88              // row stride in halves (16B-aligned rows for b128)
#define NROWS 74             // staged rows (64 outputs + 10 halo)
#define NLD 12               // staging float4 loads per thread (2960/256 = 11.6)

__device__ __forceinline__ f16x4 cvt4(f32x4 a)
{
    union { fp16x2 h2[2]; f16x4 f; } u;
    u.h2[0] = __builtin_amdgcn_cvt_pkrtz(a[0], a[1]);
    u.h2[1] = __builtin_amdgcn_cvt_pkrtz(a[2], a[3]);
    return u.f;
}

// ---- single compute kernel: 64x64 output region per block (2 x 64x32 tiles), 4 waves.
// H-pass: one mfma_f32_16x16x32_f16 per quantity; D-frag (row=4g+j) feeds vertical
// 16x16x16 B-frags directly in registers (validated R3/R5-R15).
// Quantities: mu1, mu2, A=conv((r+d)^2), B=conv((r-d)^2).
// Weights computed in-block (R15-validated). ONE fire-and-forget atomic per block.
__global__ __launch_bounds__(256, 4) void ssim_main(
    const float* __restrict__ raw, const float* __restrict__ dst,
    const float* __restrict__ win, float* __restrict__ out, float inv)
{
    __shared__ __align__(16) _Float16 sr[NROWS * SSTR];
    __shared__ __align__(16) _Float16 sd[NROWS * SSTR];
    __shared__ float w1s[11];
    __shared__ float sred[4];

    const int tid = threadIdx.x;
    const int wv = tid >> 6;           // wave = 16-wide x-strip
    const int lane = tid & 63;
    const int g = lane >> 4;
    const int ln = lane & 15;
    const int nt = wv;

    const int gx0 = blockIdx.x * 64;
    const int ybase32 = blockIdx.y * 64;        // first input row of the region
    const long ioff = (long)blockIdx.z * (512 * 512);
    const float* rb = raw + ioff;
    const float* db = dst + ioff;

    // 1D gaussian row-sums -> LDS (11 threads; visibility covered by staging barrier)
    if (tid >= 245) {
        int i = tid - 245;             // 0..10
        float s = 0.f;
#pragma unroll
        for (int j = 0; j < 11; ++j) s += win[i * 11 + j];
        w1s[i] = s;
    }

    // ---- staging: 74 rows x {r,d} x 20 float4 chunks = 2960 tasks.
    // Phase 1: issue ALL loads (max MLP); fast path (49/64 blocks) has no clamps.
    // Phase 2: pack f32->f16, write LDS. One barrier.
    float4 fv[NLD];
    const bool fastpath = (gx0 < 448) && (ybase32 < 448);
    if (fastpath) {
#pragma unroll
        for (int k = 0; k < NLD; ++k) {
            int t = tid + 256 * k;
            if (k < NLD - 1 || t < 2960) {
                int chunk = t % 20;
                int sub = t / 20;          // 0..147
                int row = sub >> 1;        // 0..73
                const float* src = (sub & 1) ? db : rb;
                fv[k] = *reinterpret_cast<const float4*>(
                    src + (long)(ybase32 + row) * 512 + gx0 + 4 * chunk);
            }
        }
    } else {
#pragma unroll
        for (int k = 0; k < NLD; ++k) {
            int t = tid + 256 * k;
            if (k < NLD - 1 || t < 2960) {
                int chunk = t % 20;
                int sub = t / 20;
                int row = sub >> 1;
                int gy = ybase32 + row; if (gy > 511) gy = 511;
                int gxc = gx0 + 4 * chunk; if (gxc > 508) gxc = 508;
                const float* src = (sub & 1) ? db : rb;
                fv[k] = *reinterpret_cast<const float4*>(src + (long)gy * 512 + gxc);
            }
        }
    }
#pragma unroll
    for (int k = 0; k < NLD; ++k) {
        int t = tid + 256 * k;
        if (k < NLD - 1 || t < 2960) {
            int chunk = t % 20;
            int sub = t / 20;
            int row = sub >> 1;
            _Float16* dstp = ((sub & 1) ? sd : sr) + row * SSTR + chunk * 4;
            union { fp16x2 h2[2]; uint2 u; } pk;
            pk.h2[0] = __builtin_amdgcn_cvt_pkrtz(fv[k].x, fv[k].y);
            pk.h2[1] = __builtin_amdgcn_cvt_pkrtz(fv[k].z, fv[k].w);
            *reinterpret_cast<uint2*>(dstp) = pk.u;
        }
    }
    __syncthreads();

    // ---- per-lane weight fragments (banded, translation-invariant; R15-validated) ----
    f16x4 wf0, wf1;
    f16x8 wh;
    {
        float v[8];
#pragma unroll
        for (int kk = 0; kk < 2; ++kk) {
            int ib = 4 * g + 16 * kk - ln;
#pragma unroll
            for (int j = 0; j < 4; ++j) {
                int idx = ib + j;
                int ci = idx < 0 ? 0 : (idx > 10 ? 10 : idx);
                float t = w1s[ci];
                v[kk * 4 + j] = (idx >= 0 && idx <= 10) ? t : 0.f;
            }
        }
        wf0 = f16x4{(_Float16)v[0], (_Float16)v[1], (_Float16)v[2], (_Float16)v[3]};
        wf1 = f16x4{(_Float16)v[4], (_Float16)v[5], (_Float16)v[6], (_Float16)v[7]};
        float h[8];
#pragma unroll
        for (int j = 0; j < 8; ++j) {
            int idx = 8 * g + j - ln;
            int ci = idx < 0 ? 0 : (idx > 10 ? 10 : idx);
            float t = w1s[ci];
            h[j] = (idx >= 0 && idx <= 10) ? t : 0.f;
        }
        wh = f16x8{(_Float16)h[0], (_Float16)h[1], (_Float16)h[2], (_Float16)h[3],
                   (_Float16)h[4], (_Float16)h[5], (_Float16)h[6], (_Float16)h[7]};
    }

    float lsum = 0.f;
    const int ox = gx0 + 16 * nt + ln;

#pragma unroll
    for (int it = 0; it < 2; ++it) {
        // ---- horizontal conv: ONE 16x16x32 MFMA per quantity per row-tile ----
        f16x4 hf0[4], hf1[4], hf2[4];
#define COMP_H(HF, MT)                                                        \
        {                                                                     \
            f32x4 z = {0, 0, 0, 0};                                           \
            int rrow = ln + 16 * (MT) + 32 * it; if (rrow > 73) rrow = 73;    \
            const f16x8 rA = *(const f16x8*)(sr + rrow * SSTR + 16 * nt + 8 * g); \
            const f16x8 dA = *(const f16x8*)(sd + rrow * SSTR + 16 * nt + 8 * g); \
            f16x8 sA = rA + dA, qA = rA - dA;                                 \
            f16x8 ss = sA * sA, qq = qA * qA;                                 \
            f32x4 a0 = __builtin_amdgcn_mfma_f32_16x16x32_f16(rA, wh, z, 0, 0, 0); \
            f32x4 a1 = __builtin_amdgcn_mfma_f32_16x16x32_f16(dA, wh, z, 0, 0, 0); \
            f32x4 a2 = __builtin_amdgcn_mfma_f32_16x16x32_f16(ss, wh, z, 0, 0, 0); \
            f32x4 a3 = __builtin_amdgcn_mfma_f32_16x16x32_f16(qq, wh, z, 0, 0, 0); \
            HF[0] = cvt4(a0); HF[1] = cvt4(a1); HF[2] = cvt4(a2); HF[3] = cvt4(a3); \
        }
        COMP_H(hf0, 0)
        COMP_H(hf1, 1)
        COMP_H(hf2, 2)
#undef COMP_H

        // ---- vertical conv (2x 16x16x16, register B-frags) + f32x2 epilogue ----
#define COMP_O(HA, HB, MTV)                                                   \
        {                                                                     \
            f32x4 z = {0, 0, 0, 0};                                           \
            f32x4 v0 = __builtin_amdgcn_mfma_f32_16x16x16f16(wf0, HA[0], z, 0, 0, 0); \
            f32x4 v1 = __builtin_amdgcn_mfma_f32_16x16x16f16(wf0, HA[1], z, 0, 0, 0); \
            f32x4 v2 = __builtin_amdgcn_mfma_f32_16x16x16f16(wf0, HA[2], z, 0, 0, 0); \
            f32x4 v3 = __builtin_amdgcn_mfma_f32_16x16x16f16(wf0, HA[3], z, 0, 0, 0); \
            v0 = __builtin_amdgcn_mfma_f32_16x16x16f16(wf1, HB[0], v0, 0, 0, 0); \
            v1 = __builtin_amdgcn_mfma_f32_16x16x16f16(wf1, HB[1], v1, 0, 0, 0); \
            v2 = __builtin_amdgcn_mfma_f32_16x16x16f16(wf1, HB[2], v2, 0, 0, 0); \
            v3 = __builtin_amdgcn_mfma_f32_16x16x16f16(wf1, HB[3], v3, 0, 0, 0); \
            int oy0 = ybase32 + 32 * it + 16 * (MTV) + 4 * g;                 \
            if (ox < 502) {                                                   \
                _Pragma("unroll")                                             \
                for (int p = 0; p < 2; ++p) {                                 \
                    f32x2 m1 = {v0[2*p], v0[2*p+1]};                          \
                    f32x2 m2 = {v1[2*p], v1[2*p+1]};                          \
                    f32x2 A  = {v2[2*p], v2[2*p+1]};                          \
                    f32x2 B  = {v3[2*p], v3[2*p+1]};                          \
                    f32x2 m1s = m1 * m1, m2s = m2 * m2, m12 = m1 * m2;        \
                    f32x2 P = m1s + m2s;                                      \
                    f32x2 num1 = 2.f * m12 + 6.5025f;                         \
                    f32x2 num2 = 0.5f * (A - B) - 2.f * m12 + 58.5225f;       \
                    f32x2 den1 = P + 6.5025f;                                 \
                    f32x2 den2 = 0.5f * (A + B) - P + 58.5225f;               \
                    f32x2 num = num1 * num2, den = den1 * den2;               \
                    if (oy0 + 2*p     < 502) lsum += __fdividef(num[0], den[0]); \
                    if (oy0 + 2*p + 1 < 502) lsum += __fdividef(num[1], den[1]); \
                }                                                             \
            }                                                                 \
        }
        COMP_O(hf0, hf1, 0)
        COMP_O(hf1, hf2, 1)
#undef COMP_O
    }

    // ---- wave reduce -> block reduce -> ONE fire-and-forget atomic per block ----
#pragma unroll
    for (int off = 32; off; off >>= 1) lsum += __shfl_down(lsum, off);
    if (lane == 0) sred[wv] = lsum;
    __syncthreads();
    if (tid == 0) {
        float s = (sred[0] + sred[1]) + (sred[2] + sred[3]);
        atomicAdd(out, s * inv);       // no return value -> combinable, no serialization
    }
}

extern "C" void kernel_launch(void* const* d_in, const int* in_sizes, int n_in,
                              void* d_out, int out_size, void* d_ws, size_t ws_size,
                              hipStream_t stream) {
    const float* raw = (const float*)d_in[0];
    const float* dst = (const float*)d_in[1];
    const float* win = (const float*)d_in[2];
    float* out = (float*)d_out;

    int nimg = in_sizes[0] / (512 * 512);      // B*C = 48
    float inv = 1.0f / ((float)nimg * 502.f * 502.f);

    hipMemsetAsync(out, 0, sizeof(float), stream);   // re-arms every replay
    dim3 grid(8, 8, nimg);
    ssim_main<<<grid, 256, 0, stream>>>(raw, dst, win, out, inv);
}

// Round 17
// 37.191 us; speedup vs baseline: 4.2923x; 1.5674x over previous
//
#include <hip/hip_runtime.h>

typedef _Float16 f16x4 __attribute__((ext_vector_type(4)));
typedef _Float16 f16x8 __attribute__((ext_vector_type(8)));
typedef __fp16 fp16x2 __attribute__((ext_vector_type(2)));   // cvt_pkrtz return type
typedef float f32x4 __attribute__((ext_vector_type(4)));
typedef float f32x2 __attribute__((ext_vector_type(2)));

#define NBUCKETS 256
#define SSTR 88              // row stride in halves (16B-aligned rows for b128)
#define NROWS 74             // staged rows (64 outputs + 10 halo)
#define NLD 12               // staging float4 loads per thread (2960/256 = 11.6)

__device__ __forceinline__ f16x4 cvt4(f32x4 a)
{
    union { fp16x2 h2[2]; f16x4 f; } u;
    u.h2[0] = __builtin_amdgcn_cvt_pkrtz(a[0], a[1]);
    u.h2[1] = __builtin_amdgcn_cvt_pkrtz(a[2], a[3]);
    return u.f;
}

// ---- main: 64x64 output region per block (2 x 64x32 tiles), 4 waves, ONE barrier.
// H-pass: one mfma_f32_16x16x32_f16 per quantity; D-frag (row=4g+j) feeds vertical
// 16x16x16 B-frags directly in registers (validated R3/R5-R16).
// Quantities: mu1, mu2, A=conv((r+d)^2), B=conv((r-d)^2).
// Weights in-block (R15/R16-validated). Scattered per-wave bucket atomics (R14-validated).
// 1D grid + XCD-bijective swizzle: each XCD owns 6 consecutive images.
__global__ __launch_bounds__(256, 4) void ssim_main(
    const float* __restrict__ raw, const float* __restrict__ dst,
    const float* __restrict__ win, float* __restrict__ buckets)
{
    __shared__ __align__(16) _Float16 sr[NROWS * SSTR];
    __shared__ __align__(16) _Float16 sd[NROWS * SSTR];
    __shared__ float w1s[11];

    const int tid = threadIdx.x;
    const int wv = tid >> 6;           // wave = 16-wide x-strip
    const int lane = tid & 63;
    const int g = lane >> 4;
    const int ln = lane & 15;
    const int nt = wv;

    // XCD-bijective swizzle: 3072 blocks = 8 XCDs x 384-contiguous runs
    const int wg = blockIdx.x;
    const int sw = (wg & 7) * 384 + (wg >> 3);
    const int bz = sw >> 6;
    const int bx = sw & 7;
    const int by = (sw >> 3) & 7;

    const int gx0 = bx * 64;
    const int ybase32 = by * 64;                // first input row of the region
    const long ioff = (long)bz * (512 * 512);
    const float* rb = raw + ioff;
    const float* db = dst + ioff;

    // 1D gaussian row-sums -> LDS (11 threads; visibility covered by staging barrier)
    if (tid >= 245) {
        int i = tid - 245;             // 0..10
        float s = 0.f;
#pragma unroll
        for (int j = 0; j < 11; ++j) s += win[i * 11 + j];
        w1s[i] = s;
    }

    // ---- staging: 74 rows x {r,d} x 20 float4 chunks = 2960 tasks.
    // Phase 1: issue ALL loads (max MLP); fast path (49/64 regions) has no clamps.
    // Phase 2: pack f32->f16, write LDS. One barrier.
    float4 fv[NLD];
    const bool fastpath = (gx0 < 448) && (ybase32 < 448);
    if (fastpath) {
#pragma unroll
        for (int k = 0; k < NLD; ++k) {
            int t = tid + 256 * k;
            if (k < NLD - 1 || t < 2960) {
                int chunk = t % 20;
                int sub = t / 20;          // 0..147
                int row = sub >> 1;        // 0..73
                const float* src = (sub & 1) ? db : rb;
                fv[k] = *reinterpret_cast<const float4*>(
                    src + (long)(ybase32 + row) * 512 + gx0 + 4 * chunk);
            }
        }
    } else {
#pragma unroll
        for (int k = 0; k < NLD; ++k) {
            int t = tid + 256 * k;
            if (k < NLD - 1 || t < 2960) {
                int chunk = t % 20;
                int sub = t / 20;
                int row = sub >> 1;
                int gy = ybase32 + row; if (gy > 511) gy = 511;
                int gxc = gx0 + 4 * chunk; if (gxc > 508) gxc = 508;
                const float* src = (sub & 1) ? db : rb;
                fv[k] = *reinterpret_cast<const float4*>(src + (long)gy * 512 + gxc);
            }
        }
    }
#pragma unroll
    for (int k = 0; k < NLD; ++k) {
        int t = tid + 256 * k;
        if (k < NLD - 1 || t < 2960) {
            int chunk = t % 20;
            int sub = t / 20;
            int row = sub >> 1;
            _Float16* dstp = ((sub & 1) ? sd : sr) + row * SSTR + chunk * 4;
            union { fp16x2 h2[2]; uint2 u; } pk;
            pk.h2[0] = __builtin_amdgcn_cvt_pkrtz(fv[k].x, fv[k].y);
            pk.h2[1] = __builtin_amdgcn_cvt_pkrtz(fv[k].z, fv[k].w);
            *reinterpret_cast<uint2*>(dstp) = pk.u;
        }
    }
    __syncthreads();

    // ---- per-lane weight fragments (banded, translation-invariant; R15-validated) ----
    f16x4 wf0, wf1;
    f16x8 wh;
    {
        float v[8];
#pragma unroll
        for (int kk = 0; kk < 2; ++kk) {
            int ib = 4 * g + 16 * kk - ln;
#pragma unroll
            for (int j = 0; j < 4; ++j) {
                int idx = ib + j;
                int ci = idx < 0 ? 0 : (idx > 10 ? 10 : idx);
                float t = w1s[ci];
                v[kk * 4 + j] = (idx >= 0 && idx <= 10) ? t : 0.f;
            }
        }
        wf0 = f16x4{(_Float16)v[0], (_Float16)v[1], (_Float16)v[2], (_Float16)v[3]};
        wf1 = f16x4{(_Float16)v[4], (_Float16)v[5], (_Float16)v[6], (_Float16)v[7]};
        float h[8];
#pragma unroll
        for (int j = 0; j < 8; ++j) {
            int idx = 8 * g + j - ln;
            int ci = idx < 0 ? 0 : (idx > 10 ? 10 : idx);
            float t = w1s[ci];
            h[j] = (idx >= 0 && idx <= 10) ? t : 0.f;
        }
        wh = f16x8{(_Float16)h[0], (_Float16)h[1], (_Float16)h[2], (_Float16)h[3],
                   (_Float16)h[4], (_Float16)h[5], (_Float16)h[6], (_Float16)h[7]};
    }

    float lsum = 0.f;
    const int ox = gx0 + 16 * nt + ln;

#pragma unroll
    for (int it = 0; it < 2; ++it) {
        // ---- horizontal conv: ONE 16x16x32 MFMA per quantity per row-tile ----
        f16x4 hf0[4], hf1[4], hf2[4];
#define COMP_H(HF, MT)                                                        \
        {                                                                     \
            f32x4 z = {0, 0, 0, 0};                                           \
            int rrow = ln + 16 * (MT) + 32 * it; if (rrow > 73) rrow = 73;    \
            const f16x8 rA = *(const f16x8*)(sr + rrow * SSTR + 16 * nt + 8 * g); \
            const f16x8 dA = *(const f16x8*)(sd + rrow * SSTR + 16 * nt + 8 * g); \
            f16x8 sA = rA + dA, qA = rA - dA;                                 \
            f16x8 ss = sA * sA, qq = qA * qA;                                 \
            f32x4 a0 = __builtin_amdgcn_mfma_f32_16x16x32_f16(rA, wh, z, 0, 0, 0); \
            f32x4 a1 = __builtin_amdgcn_mfma_f32_16x16x32_f16(dA, wh, z, 0, 0, 0); \
            f32x4 a2 = __builtin_amdgcn_mfma_f32_16x16x32_f16(ss, wh, z, 0, 0, 0); \
            f32x4 a3 = __builtin_amdgcn_mfma_f32_16x16x32_f16(qq, wh, z, 0, 0, 0); \
            HF[0] = cvt4(a0); HF[1] = cvt4(a1); HF[2] = cvt4(a2); HF[3] = cvt4(a3); \
        }
        COMP_H(hf0, 0)
        COMP_H(hf1, 1)
        COMP_H(hf2, 2)
#undef COMP_H

        // ---- vertical conv (2x 16x16x16, register B-frags) + f32x2 epilogue ----
#define COMP_O(HA, HB, MTV)                                                   \
        {                                                                     \
            f32x4 z = {0, 0, 0, 0};                                           \
            f32x4 v0 = __builtin_amdgcn_mfma_f32_16x16x16f16(wf0, HA[0], z, 0, 0, 0); \
            f32x4 v1 = __builtin_amdgcn_mfma_f32_16x16x16f16(wf0, HA[1], z, 0, 0, 0); \
            f32x4 v2 = __builtin_amdgcn_mfma_f32_16x16x16f16(wf0, HA[2], z, 0, 0, 0); \
            f32x4 v3 = __builtin_amdgcn_mfma_f32_16x16x16f16(wf0, HA[3], z, 0, 0, 0); \
            v0 = __builtin_amdgcn_mfma_f32_16x16x16f16(wf1, HB[0], v0, 0, 0, 0); \
            v1 = __builtin_amdgcn_mfma_f32_16x16x16f16(wf1, HB[1], v1, 0, 0, 0); \
            v2 = __builtin_amdgcn_mfma_f32_16x16x16f16(wf1, HB[2], v2, 0, 0, 0); \
            v3 = __builtin_amdgcn_mfma_f32_16x16x16f16(wf1, HB[3], v3, 0, 0, 0); \
            int oy0 = ybase32 + 32 * it + 16 * (MTV) + 4 * g;                 \
            if (ox < 502) {                                                   \
                _Pragma("unroll")                                             \
                for (int p = 0; p < 2; ++p) {                                 \
                    f32x2 m1 = {v0[2*p], v0[2*p+1]};                          \
                    f32x2 m2 = {v1[2*p], v1[2*p+1]};                          \
                    f32x2 A  = {v2[2*p], v2[2*p+1]};                          \
                    f32x2 B  = {v3[2*p], v3[2*p+1]};                          \
                    f32x2 m1s = m1 * m1, m2s = m2 * m2, m12 = m1 * m2;        \
                    f32x2 P = m1s + m2s;                                      \
                    f32x2 num1 = 2.f * m12 + 6.5025f;                         \
                    f32x2 num2 = 0.5f * (A - B) - 2.f * m12 + 58.5225f;       \
                    f32x2 den1 = P + 6.5025f;                                 \
                    f32x2 den2 = 0.5f * (A + B) - P + 58.5225f;               \
                    f32x2 num = num1 * num2, den = den1 * den2;               \
                    if (oy0 + 2*p     < 502) lsum += __fdividef(num[0], den[0]); \
                    if (oy0 + 2*p + 1 < 502) lsum += __fdividef(num[1], den[1]); \
                }                                                             \
            }                                                                 \
        }
        COMP_O(hf0, hf1, 0)
        COMP_O(hf1, hf2, 1)
#undef COMP_O
    }

    // ---- wave reduce -> SCATTERED fire-and-forget bucket atomic (R14-validated) ----
#pragma unroll
    for (int off = 32; off; off >>= 1) lsum += __shfl_down(lsum, off);
    if (lane == 0) {
        int bucket = (wg * 4 + wv) & (NBUCKETS - 1);
        atomicAdd(&buckets[bucket], lsum);
    }
}

__global__ void ssim_finalize(const float* __restrict__ buckets,
                              float* __restrict__ out, float inv)
{
    int t = threadIdx.x;
    float s = 0.f;
    for (int i = t; i < NBUCKETS; i += 64) s += buckets[i];
#pragma unroll
    for (int off = 32; off; off >>= 1) s += __shfl_down(s, off);
    if (t == 0) out[0] = s * inv;
}

extern "C" void kernel_launch(void* const* d_in, const int* in_sizes, int n_in,
                              void* d_out, int out_size, void* d_ws, size_t ws_size,
                              hipStream_t stream) {
    const float* raw = (const float*)d_in[0];
    const float* dst = (const float*)d_in[1];
    const float* win = (const float*)d_in[2];
    float* out = (float*)d_out;
    float* ws = (float*)d_ws;

    int nimg = in_sizes[0] / (512 * 512);      // B*C = 48
    float inv = 1.0f / ((float)nimg * 502.f * 502.f);
    int nwg = 64 * nimg;                       // 8x8 regions per image

    hipMemsetAsync(ws, 0, NBUCKETS * sizeof(float), stream);   // zero buckets
    ssim_main<<<nwg, 256, 0, stream>>>(raw, dst, win, ws);
    ssim_finalize<<<1, 64, 0, stream>>>(ws, out, inv);
}